// Round 23
// baseline (300.933 us; speedup 1.0000x reference)
//
#include <hip/hip_runtime.h>
#include <hip/hip_bf16.h>
#include <cmath>

#define TK 12
#define NROW 12288
#define NEG_BIG (-3.0e38f)
#define MFMA16(a,b,c) __builtin_amdgcn_mfma_f32_16x16x32_f16(a,b,c,0,0,0)

#define NCH 8
#define CTILES 96
#define NPH 48
#define NGRP_TOT 384
#define CAP 256

typedef _Float16 f16x8 __attribute__((ext_vector_type(8)));
typedef _Float16 f16x4 __attribute__((ext_vector_type(4)));
typedef float    f32x4 __attribute__((ext_vector_type(4)));

typedef __attribute__((address_space(1))) const void gvoid_t;
typedef __attribute__((address_space(3))) void lvoid_t;
__device__ __forceinline__ void gload_lds16(const void* g, void* l) {
    __builtin_amdgcn_global_load_lds((gvoid_t*)g, (lvoid_t*)l, 16, 0, 0);
}

__device__ __forceinline__ float ftanh(float x) {
    float e = __expf(2.f * x);               // native v_exp; inf/0 saturate to +/-1
    return 1.f - __fdividef(2.f, e + 1.f);
}

// ---------------------------------------------------------------------------
// wpack_all: single launch packing all five weights into fragment layout.
// blocks 0..127  : wsi (1024x256, nkt=32)
// blocks 128..255: wh/wt/w1/w2 (256x256, nkt=8), m=(bx-128)>>5
// ---------------------------------------------------------------------------
__global__ __launch_bounds__(256) void wpack_all(
    const float* __restrict__ Wsi, _Float16* __restrict__ wsiH,
    _Float16* __restrict__ wsiL,
    const float* __restrict__ W0, const float* __restrict__ W1,
    const float* __restrict__ W2, const float* __restrict__ W3,
    _Float16* __restrict__ base)
{
    const int bx = blockIdx.x;
    if (bx < 128) {
        const int tid = bx * 256 + threadIdx.x;       // 0..32767
        const int l = tid & 63;
        const int s = (tid >> 6) & 31;                // nkt = 32
        const int cg = tid >> 11;
        const int krow = s * 32 + 8 * (l >> 4);
        const int col = cg * 16 + (l & 15);
        f16x8 H, L;
        #pragma unroll
        for (int j = 0; j < 8; ++j) {
            float w = Wsi[(size_t)(krow + j) * 256 + col];
            _Float16 h = (_Float16)w;
            H[j] = h;
            L[j] = (_Float16)(w - (float)h);
        }
        *(f16x8*)(wsiH + (size_t)tid * 8) = H;
        *(f16x8*)(wsiL + (size_t)tid * 8) = L;
    } else {
        const int m = (bx - 128) >> 5;
        const float* W = (m == 0) ? W0 : (m == 1) ? W1 : (m == 2) ? W2 : W3;
        _Float16* hi = base + (size_t)m * 131072;
        _Float16* lo = hi + 65536;
        const int tid = ((bx - 128) & 31) * 256 + threadIdx.x;   // 0..8191
        const int l = tid & 63;
        const int s = (tid >> 6) & 7;                 // nkt = 8
        const int cg = tid >> 9;
        const int krow = s * 32 + 8 * (l >> 4);
        const int col = cg * 16 + (l & 15);
        f16x8 H, L;
        #pragma unroll
        for (int j = 0; j < 8; ++j) {
            float w = W[(size_t)(krow + j) * 256 + col];
            _Float16 h = (_Float16)w;
            H[j] = h;
            L[j] = (_Float16)(w - (float)h);
        }
        *(f16x8*)(hi + (size_t)tid * 8) = H;
        *(f16x8*)(lo + (size_t)tid * 8) = L;
    }
}

// ---------------------------------------------------------------------------
// gemm_k1: C = relu( A @ W + bias ), K=1024. Grid (2,192): 64 rows x 128
// cols per block; wave owns 2 colgroups -> x is streamed only 2x.
// ---------------------------------------------------------------------------
__global__ __launch_bounds__(256) void gemm_k1(
    const float* __restrict__ A1,
    const _Float16* __restrict__ Wh, const _Float16* __restrict__ Wl,
    const float* __restrict__ bias, float* __restrict__ C, int K)
{
    __shared__ _Float16 aH[2048], aL[2048];
    __shared__ _Float16 wH[4096], wL[4096];
    const int tid = threadIdx.x, lane = tid & 63, wave = tid >> 6;
    const int rb = blockIdx.y * 64;
    const int cbg = blockIdx.x * 8;
    const int nkt = K >> 5;                       // 32

    const int arow = rb + wave * 16 + (lane & 15);
    const int acol0 = 8 * (lane >> 4);
    const float* a1p = A1 + (size_t)arow * K + acol0;

    const int slot0 = tid, slot1 = tid + 256;
    const size_t wbase0 = ((size_t)(cbg + (slot0 >> 6)) * nkt) * 512 + (slot0 & 63) * 8;
    const size_t wbase1 = ((size_t)(cbg + (slot1 >> 6)) * nkt) * 512 + (slot1 & 63) * 8;

    f32x4 acc[4][2];
    #pragma unroll
    for (int rg = 0; rg < 4; ++rg) {
        acc[rg][0] = (f32x4){0.f,0.f,0.f,0.f};
        acc[rg][1] = (f32x4){0.f,0.f,0.f,0.f};
    }

    float4 pa0 = *(const float4*)(a1p);
    float4 pa1 = *(const float4*)(a1p + 4);
    f16x8 pw0h = *(const f16x8*)(Wh + wbase0);
    f16x8 pw0l = *(const f16x8*)(Wl + wbase0);
    f16x8 pw1h = *(const f16x8*)(Wh + wbase1);
    f16x8 pw1l = *(const f16x8*)(Wl + wbase1);

    for (int kt = 0; kt < nkt; ++kt) {
        __syncthreads();
        {
            float v[8] = {pa0.x, pa0.y, pa0.z, pa0.w, pa1.x, pa1.y, pa1.z, pa1.w};
            f16x8 H, L;
            #pragma unroll
            for (int j = 0; j < 8; ++j) {
                _Float16 h = (_Float16)v[j];
                H[j] = h;
                L[j] = (_Float16)(v[j] - (float)h);
            }
            *(f16x8*)&aH[tid*8] = H;
            *(f16x8*)&aL[tid*8] = L;
            *(f16x8*)&wH[slot0*8] = pw0h;
            *(f16x8*)&wL[slot0*8] = pw0l;
            *(f16x8*)&wH[slot1*8] = pw1h;
            *(f16x8*)&wL[slot1*8] = pw1l;
        }
        __syncthreads();
        if (kt + 1 < nkt) {
            pa0 = *(const float4*)(a1p + (kt+1)*32);
            pa1 = *(const float4*)(a1p + (kt+1)*32 + 4);
            pw0h = *(const f16x8*)(Wh + wbase0 + (size_t)(kt+1)*512);
            pw0l = *(const f16x8*)(Wl + wbase0 + (size_t)(kt+1)*512);
            pw1h = *(const f16x8*)(Wh + wbase1 + (size_t)(kt+1)*512);
            pw1l = *(const f16x8*)(Wl + wbase1 + (size_t)(kt+1)*512);
        }
        f16x8 whA = *(const f16x8*)&wH[((wave*2+0)*64 + lane)*8];
        f16x8 wlA = *(const f16x8*)&wL[((wave*2+0)*64 + lane)*8];
        f16x8 whB = *(const f16x8*)&wH[((wave*2+1)*64 + lane)*8];
        f16x8 wlB = *(const f16x8*)&wL[((wave*2+1)*64 + lane)*8];
        #pragma unroll
        for (int rg = 0; rg < 4; ++rg) {
            f16x8 ah = *(const f16x8*)&aH[(rg*64 + lane)*8];
            f16x8 al = *(const f16x8*)&aL[(rg*64 + lane)*8];
            acc[rg][0] = MFMA16(whA, ah, acc[rg][0]);
            acc[rg][0] = MFMA16(wlA, ah, acc[rg][0]);
            acc[rg][0] = MFMA16(whA, al, acc[rg][0]);
            acc[rg][1] = MFMA16(whB, ah, acc[rg][1]);
            acc[rg][1] = MFMA16(wlB, ah, acc[rg][1]);
            acc[rg][1] = MFMA16(whB, al, acc[rg][1]);
        }
    }
    #pragma unroll
    for (int c = 0; c < 2; ++c) {
        const int col = (cbg + wave*2 + c)*16 + 4*(lane >> 4);
        float4 b4 = *(const float4*)(bias + col);
        #pragma unroll
        for (int rg = 0; rg < 4; ++rg) {
            const int row = rb + rg*16 + (lane & 15);
            float4 o;
            o.x = fmaxf(acc[rg][c][0] + b4.x, 0.f);
            o.y = fmaxf(acc[rg][c][1] + b4.y, 0.f);
            o.z = fmaxf(acc[rg][c][2] + b4.z, 0.f);
            o.w = fmaxf(acc[rg][c][3] + b4.w, 0.f);
            *(float4*)(C + (size_t)row*256 + col) = o;
        }
    }
}

// ---------------------------------------------------------------------------
// gemm_dual: K=N=256 fused pair, register-prefetched staging.
//  DMODE 0: C1 = A1@W1+b1 ; C2 = A1@W2+b2 ; packs C1*SCALE->P1, C2->P2.
//  DMODE 1: C1 = relu((A1+A2)@W1+b1) + relu((A1*A2)@W2+b2)
// ---------------------------------------------------------------------------
template<int DMODE>
__global__ __launch_bounds__(256) void gemm_dual(
    const float* __restrict__ A1, const float* __restrict__ A2,
    const _Float16* __restrict__ W1h, const _Float16* __restrict__ W1l,
    const _Float16* __restrict__ W2h, const _Float16* __restrict__ W2l,
    const float* __restrict__ bias1, const float* __restrict__ bias2,
    float* __restrict__ C1, float* __restrict__ C2,
    _Float16* __restrict__ P1, _Float16* __restrict__ P2)
{
    __shared__ _Float16 aH[2][2048], aL[2][2048];
    __shared__ _Float16 wH[2][2048], wL[2][2048];
    const int tid = threadIdx.x, lane = tid & 63, wave = tid >> 6;
    const int rb = blockIdx.y * 64;
    const int cbg = blockIdx.x * 4;

    const int arow = rb + wave * 16 + (lane & 15);
    const int acol0 = 8 * (lane >> 4);
    const float* a1p = A1 + (size_t)arow * 256 + acol0;
    const float* a2p = (DMODE == 1) ? (A2 + (size_t)arow * 256 + acol0) : nullptr;
    const size_t wbase = ((size_t)(cbg + wave) * 8) * 512 + lane * 8;

    f32x4 acc1[4], acc2[4];
    #pragma unroll
    for (int rg = 0; rg < 4; ++rg) {
        acc1[rg] = (f32x4){0.f,0.f,0.f,0.f};
        acc2[rg] = (f32x4){0.f,0.f,0.f,0.f};
    }

    float4 pa0 = *(const float4*)(a1p);
    float4 pa1 = *(const float4*)(a1p + 4);
    float4 pb0, pb1;
    if (DMODE == 1) { pb0 = *(const float4*)(a2p); pb1 = *(const float4*)(a2p + 4); }
    f16x8 pw1h = *(const f16x8*)(W1h + wbase);
    f16x8 pw1l = *(const f16x8*)(W1l + wbase);
    f16x8 pw2h = *(const f16x8*)(W2h + wbase);
    f16x8 pw2l = *(const f16x8*)(W2l + wbase);

    for (int kt = 0; kt < 8; ++kt) {
        __syncthreads();
        {
            float v[8] = {pa0.x, pa0.y, pa0.z, pa0.w, pa1.x, pa1.y, pa1.z, pa1.w};
            if (DMODE == 0) {
                f16x8 H, L;
                #pragma unroll
                for (int j = 0; j < 8; ++j) {
                    _Float16 h = (_Float16)v[j];
                    H[j] = h;
                    L[j] = (_Float16)(v[j] - (float)h);
                }
                *(f16x8*)&aH[0][tid*8] = H;
                *(f16x8*)&aL[0][tid*8] = L;
            } else {
                float b[8] = {pb0.x, pb0.y, pb0.z, pb0.w, pb1.x, pb1.y, pb1.z, pb1.w};
                f16x8 Hs, Ls, Hm, Lm;
                #pragma unroll
                for (int j = 0; j < 8; ++j) {
                    float s = v[j] + b[j];
                    float m = v[j] * b[j];
                    _Float16 hs = (_Float16)s;
                    _Float16 hm = (_Float16)m;
                    Hs[j] = hs; Ls[j] = (_Float16)(s - (float)hs);
                    Hm[j] = hm; Lm[j] = (_Float16)(m - (float)hm);
                }
                *(f16x8*)&aH[0][tid*8] = Hs;
                *(f16x8*)&aL[0][tid*8] = Ls;
                *(f16x8*)&aH[1][tid*8] = Hm;
                *(f16x8*)&aL[1][tid*8] = Lm;
            }
            *(f16x8*)&wH[0][tid*8] = pw1h;
            *(f16x8*)&wL[0][tid*8] = pw1l;
            *(f16x8*)&wH[1][tid*8] = pw2h;
            *(f16x8*)&wL[1][tid*8] = pw2l;
        }
        __syncthreads();
        if (kt + 1 < 8) {
            pa0 = *(const float4*)(a1p + (kt+1)*32);
            pa1 = *(const float4*)(a1p + (kt+1)*32 + 4);
            if (DMODE == 1) {
                pb0 = *(const float4*)(a2p + (kt+1)*32);
                pb1 = *(const float4*)(a2p + (kt+1)*32 + 4);
            }
            pw1h = *(const f16x8*)(W1h + wbase + (size_t)(kt+1)*512);
            pw1l = *(const f16x8*)(W1l + wbase + (size_t)(kt+1)*512);
            pw2h = *(const f16x8*)(W2h + wbase + (size_t)(kt+1)*512);
            pw2l = *(const f16x8*)(W2l + wbase + (size_t)(kt+1)*512);
        }
        f16x8 w1h = *(const f16x8*)&wH[0][(wave*64 + lane)*8];
        f16x8 w1l = *(const f16x8*)&wL[0][(wave*64 + lane)*8];
        f16x8 w2h = *(const f16x8*)&wH[1][(wave*64 + lane)*8];
        f16x8 w2l = *(const f16x8*)&wL[1][(wave*64 + lane)*8];
        #pragma unroll
        for (int rg = 0; rg < 4; ++rg) {
            f16x8 ah0 = *(const f16x8*)&aH[0][(rg*64 + lane)*8];
            f16x8 al0 = *(const f16x8*)&aL[0][(rg*64 + lane)*8];
            acc1[rg] = MFMA16(w1h, ah0, acc1[rg]);
            acc1[rg] = MFMA16(w1l, ah0, acc1[rg]);
            acc1[rg] = MFMA16(w1h, al0, acc1[rg]);
            f16x8 ah1 = (DMODE == 1) ? *(const f16x8*)&aH[1][(rg*64 + lane)*8] : ah0;
            f16x8 al1 = (DMODE == 1) ? *(const f16x8*)&aL[1][(rg*64 + lane)*8] : al0;
            acc2[rg] = MFMA16(w2h, ah1, acc2[rg]);
            acc2[rg] = MFMA16(w2l, ah1, acc2[rg]);
            acc2[rg] = MFMA16(w2h, al1, acc2[rg]);
        }
    }
    const int col = (cbg + wave)*16 + 4*(lane >> 4);
    float4 b14 = *(const float4*)(bias1 + col);
    float4 b24 = *(const float4*)(bias2 + col);
    #pragma unroll
    for (int rg = 0; rg < 4; ++rg) {
        const int row = rb + rg*16 + (lane & 15);
        if (DMODE == 0) {
            float4 o1, o2;
            o1.x = acc1[rg][0] + b14.x; o1.y = acc1[rg][1] + b14.y;
            o1.z = acc1[rg][2] + b14.z; o1.w = acc1[rg][3] + b14.w;
            o2.x = acc2[rg][0] + b24.x; o2.y = acc2[rg][1] + b24.y;
            o2.z = acc2[rg][2] + b24.z; o2.w = acc2[rg][3] + b24.w;
            *(float4*)(C1 + (size_t)row*256 + col) = o1;
            *(float4*)(C2 + (size_t)row*256 + col) = o2;
            const size_t poff = ((size_t)(row >> 4)*8 + (col >> 5))*512
                              + (((col & 31) >> 3)*16 + (row & 15))*8 + (col & 7);
            f16x4 p1, p2;
            p1[0] = (_Float16)(o1.x * 0.0625f); p1[1] = (_Float16)(o1.y * 0.0625f);
            p1[2] = (_Float16)(o1.z * 0.0625f); p1[3] = (_Float16)(o1.w * 0.0625f);
            p2[0] = (_Float16)o2.x; p2[1] = (_Float16)o2.y;
            p2[2] = (_Float16)o2.z; p2[3] = (_Float16)o2.w;
            *(f16x4*)(P1 + poff) = p1;
            *(f16x4*)(P2 + poff) = p2;
        } else {
            float4 o;
            o.x = fmaxf(acc1[rg][0] + b14.x, 0.f) + fmaxf(acc2[rg][0] + b24.x, 0.f);
            o.y = fmaxf(acc1[rg][1] + b14.y, 0.f) + fmaxf(acc2[rg][1] + b24.y, 0.f);
            o.z = fmaxf(acc1[rg][2] + b14.z, 0.f) + fmaxf(acc2[rg][2] + b24.z, 0.f);
            o.w = fmaxf(acc1[rg][3] + b14.w, 0.f) + fmaxf(acc2[rg][3] + b24.w, 0.f);
            *(float4*)(C1 + (size_t)row*256 + col) = o;
        }
    }
}

// ---------------------------------------------------------------------------
// S1 (rs=2, TOP-2, 2-buffer depth-1 prefetch): per 32-col group and row,
// record (max1, col1, max2) into g32[row*384+g] and gcol (u8 col1).
// LDS = 2 x 16KB (was 3x16KB) -> all 3 blocks/CU co-resident. Loads for
// phase p+1 issue at phase-p start (overlap compute); stores at flush end;
// one vmcnt(0) per phase end. Register-buffered 8-phase flush (32B+8B runs).
// Grid = 8 chunks x 96 rowblocks = 768 blocks, 128 rows/block.
// ---------------------------------------------------------------------------
__global__ __launch_bounds__(256, 2) void s1_gmax(
    const _Float16* __restrict__ ehh, const _Float16* __restrict__ eth,
    unsigned* __restrict__ g32, unsigned char* __restrict__ gcol)
{
    __shared__ _Float16 abuf[2][8192];          // 2 x 16KB phase buffers
    const int tid = threadIdx.x, lane = tid & 63, wave = tid >> 6;
    const int chunk = blockIdx.x & (NCH-1);     // == XCD id (L2 affinity)
    const int rblk = blockIdx.x >> 3;           // 0..95
    const int rg0 = rblk * 8 + wave * 2;

    f16x8 bh[2][8];
    #pragma unroll
    for (int rs = 0; rs < 2; ++rs) {
        const _Float16* p = ehh + (size_t)(rg0 + rs)*4096 + lane*8;
        #pragma unroll
        for (int s = 0; s < 8; ++s) bh[rs][s] = *(const f16x8*)(p + s*512);
    }
    #pragma unroll
    for (int rs = 0; rs < 2; ++rs)
        #pragma unroll
        for (int s = 0; s < 8; ++s)
            asm volatile("" : "+v"(bh[rs][s]));

    const int rsw = (lane >> 4) & 1;
    const int myrow = (rg0 + rsw)*16 + (lane & 15);
    const size_t rowbase = (size_t)myrow*NGRP_TOT + chunk*NPH;

    const _Float16* gsrc = eth + (size_t)chunk * CTILES * 4096;
    // prologue: stage phase 0 into buf0
    #pragma unroll
    for (int i = 0; i < 4; ++i) {
        const int u = wave*4 + i;
        gload_lds16(gsrc + (size_t)(u>>3)*4096 + (u&7)*512 + lane*8,
                    &abuf[0][u*512]);
    }
    asm volatile("s_waitcnt vmcnt(0) lgkmcnt(0)" ::: "memory");
    __builtin_amdgcn_s_barrier();
    asm volatile("" ::: "memory");

    int cur = 0;
    for (int pp = 0; pp < 6; ++pp) {
        unsigned resv[8];
        unsigned long long colv = 0;
        #pragma unroll
        for (int q = 0; q < 8; ++q) {
            const int p = pp*8 + q;
            if (p + 1 < NPH) {
                #pragma unroll
                for (int i = 0; i < 4; ++i) {
                    const int u = wave*4 + i;
                    gload_lds16(gsrc + (size_t)((p+1)*2 + (u>>3))*4096 + (u&7)*512 + lane*8,
                                &abuf[cur ^ 1][u*512]);
                }
            }
            float m1a = NEG_BIG, m2a = NEG_BIG; int mca = 0;
            float m1b = NEG_BIG, m2b = NEG_BIG; int mcb = 0;
            #pragma unroll
            for (int tt = 0; tt < 2; ++tt) {
                f32x4 aE[2], aO[2];
                #pragma unroll
                for (int rs = 0; rs < 2; ++rs) {
                    aE[rs] = (f32x4){0.f,0.f,0.f,0.f};
                    aO[rs] = (f32x4){0.f,0.f,0.f,0.f};
                }
                #pragma unroll
                for (int s = 0; s < 8; ++s) {
                    f16x8 ah = *(const f16x8*)&abuf[cur][tt*4096 + s*512 + lane*8];
                    if (s & 1) {
                        aO[0] = MFMA16(ah, bh[0][s], aO[0]);
                        aO[1] = MFMA16(ah, bh[1][s], aO[1]);
                    } else {
                        aE[0] = MFMA16(ah, bh[0][s], aE[0]);
                        aE[1] = MFMA16(ah, bh[1][s], aE[1]);
                    }
                }
                f32x4 a0 = aE[0] + aO[0];
                f32x4 a1 = aE[1] + aO[1];
                const int cb = tt*16 + 4*(lane >> 4);
                #pragma unroll
                for (int e = 0; e < 4; ++e) {
                    bool g0 = a0[e] > m1a;
                    m2a = fmaxf(m2a, g0 ? m1a : a0[e]);
                    mca = g0 ? (cb + e) : mca;
                    m1a = fmaxf(m1a, a0[e]);
                    bool g1 = a1[e] > m1b;
                    m2b = fmaxf(m2b, g1 ? m1b : a1[e]);
                    mcb = g1 ? (cb + e) : mcb;
                    m1b = fmaxf(m1b, a1[e]);
                }
            }
            #pragma unroll
            for (int k = 16; k <= 32; k <<= 1) {
                float o1 = __shfl_xor(m1a, k); int oc = __shfl_xor(mca, k);
                float o2 = __shfl_xor(m2a, k);
                bool gt = o1 > m1a;
                m2a = fmaxf(fmaxf(m2a, o2), gt ? m1a : o1);
                mca = gt ? oc : mca;
                m1a = fmaxf(m1a, o1);
                float p1 = __shfl_xor(m1b, k); int pc = __shfl_xor(mcb, k);
                float p2 = __shfl_xor(m2b, k);
                bool ht = p1 > m1b;
                m2b = fmaxf(fmaxf(m2b, p2), ht ? m1b : p1);
                mcb = ht ? pc : mcb;
                m1b = fmaxf(m1b, p1);
            }
            {
                float M1 = rsw ? m1b : m1a;
                float M2 = rsw ? m2b : m2a;
                int   MC = rsw ? mcb : mca;
                unsigned short h1 = __builtin_bit_cast(unsigned short, (_Float16)M1);
                unsigned short h2 = __builtin_bit_cast(unsigned short, (_Float16)M2);
                resv[q] = ((unsigned)h1 << 16) | h2;
                colv |= (unsigned long long)(unsigned char)MC << (8*q);
            }
            if (q == 7 && lane < 32) {
                const size_t base = rowbase + pp*8;
                uint4 v0; v0.x = resv[0]; v0.y = resv[1]; v0.z = resv[2]; v0.w = resv[3];
                uint4 v1; v1.x = resv[4]; v1.y = resv[5]; v1.z = resv[6]; v1.w = resv[7];
                *(uint4*)(g32 + base)     = v0;
                *(uint4*)(g32 + base + 4) = v1;
                *(unsigned long long*)(gcol + base) = colv;
            }
            asm volatile("s_waitcnt vmcnt(0)" ::: "memory");
            __builtin_amdgcn_s_barrier();
            asm volatile("" ::: "memory");
            cur ^= 1;
        }
    }
    asm volatile("s_waitcnt vmcnt(0)" ::: "memory");
}

// ---------------------------------------------------------------------------
// B2 (wave-per-row): tau = (12th-largest max1) - margin; emit candidates.
// Grid = 3072 blocks x 4 waves.
// ---------------------------------------------------------------------------
__global__ __launch_bounds__(256) void b2_emit(
    const unsigned* __restrict__ g32, const unsigned char* __restrict__ gcol,
    unsigned* __restrict__ cnt, int* __restrict__ cand)
{
    const int lane = threadIdx.x & 63;
    const int wave = threadIdx.x >> 6;
    const int row  = blockIdx.x * 4 + wave;

    const unsigned* gr = g32 + (size_t)row*NGRP_TOT + lane*6;
    uint2 u0 = *(const uint2*)gr;
    uint2 u1 = *(const uint2*)(gr + 2);
    uint2 u2 = *(const uint2*)(gr + 4);
    unsigned uu[6] = {u0.x, u0.y, u1.x, u1.y, u2.x, u2.y};
    float m1[6], m2[6];
    #pragma unroll
    for (int i = 0; i < 6; ++i) {
        m1[i] = (float)__builtin_bit_cast(_Float16, (unsigned short)(uu[i] >> 16));
        m2[i] = (float)__builtin_bit_cast(_Float16, (unsigned short)(uu[i] & 0xffffu));
    }

    float sl[6];
    #pragma unroll
    for (int j = 0; j < 6; ++j) sl[j] = NEG_BIG;
    #pragma unroll
    for (int i = 0; i < 6; ++i) {
        float v = m1[i];
        #pragma unroll
        for (int j = 5; j >= 1; --j)
            sl[j] = __builtin_amdgcn_fmed3f(v, sl[j], sl[j-1]);
        sl[0] = fmaxf(v, sl[0]);
    }

    int hi = 0;
    float t12 = NEG_BIG;
    #pragma unroll 1
    for (int o = 0; o < TK; ++o) {
        float head = (hi < 6) ? sl[hi] : NEG_BIG;
        float bv = head; int bl = lane;
        #pragma unroll
        for (int off = 1; off <= 32; off <<= 1) {
            float ov = __shfl_xor(bv, off);
            int   ol = __shfl_xor(bl, off);
            bool take = (ov > bv) || (ov == bv && ol < bl);
            bv = take ? ov : bv;
            bl = take ? ol : bl;
        }
        if (lane == bl) hi++;
        t12 = bv;
    }
    const float tau = t12 - 0.02f;

    int n = 0;
    int* crow = cand + (size_t)row * CAP;
    #pragma unroll 1
    for (int i = 0; i < 6; ++i) {
        const bool hit1 = m1[i] >= tau;
        const bool expn = hit1 && (m2[i] >= tau);
        const bool single = hit1 && !expn;
        unsigned long long ms = __ballot(single);
        if (single) {
            const int pos = n + __popcll(ms & ((1ull << lane) - 1ull));
            if (pos < CAP) {
                const int g = lane*6 + i;
                crow[pos] = g*32 + (int)gcol[(size_t)row*NGRP_TOT + g];
            }
        }
        n += __popcll(ms);
        unsigned long long me = __ballot(expn);
        while (me) {
            const int src = __builtin_ctzll(me);
            me &= me - 1ull;
            const int cb = (src*6 + i) * 32;
            if (lane < 32) {
                const int pos = n + lane;
                if (pos < CAP) crow[pos] = cb + lane;
            }
            n += 32;
        }
    }
    if (lane == 0) cnt[row] = (unsigned)((n < CAP) ? n : CAP);
}

// ---------------------------------------------------------------------------
// S3 (scattered + FAST tanh/exp): exact f32 rescoring of up to 256
// candidates (4 per lane), exact top-12 (val desc, col asc), softmax /
// gather / tanh-gate / ka-softmax / e_Nh. One wave per row, 4 rows/block.
// ---------------------------------------------------------------------------
__global__ __launch_bounds__(256) void s3_tail(
    const float* __restrict__ e_h, const float* __restrict__ e_t,
    const unsigned int* __restrict__ cnt, const int* __restrict__ cand,
    float* __restrict__ e_Nh)
{
    const int lane = threadIdx.x & 63;
    const int wave = threadIdx.x >> 6;
    const int row  = blockIdx.x * 4 + wave;

    const unsigned cn = min(cnt[row], (unsigned)CAP);
    const float* ehr = e_h + (size_t)row * 256;

    float v[4]; int c[4];
    #pragma unroll
    for (int i = 0; i < 4; ++i) {
        const int idx = lane + 64*i;
        const bool act = idx < (int)cn;
        c[i] = act ? cand[(size_t)row*CAP + idx] : (0x7ffffff0 + i);
        v[i] = NEG_BIG;
        if ((int)cn > 64*i) {                    // wave-uniform chunk guard
            const float* etr = e_t + (size_t)(act ? c[i] : 0) * 256;
            float s = 0.f;
            for (int k = 0; k < 64; ++k) {
                float4 a = *(const float4*)(ehr + k*4);
                float4 b = *(const float4*)(etr + k*4);
                s += a.x*b.x + a.y*b.y + a.z*b.z + a.w*b.w;
            }
            if (act) v[i] = s * 0.0625f;
        }
    }

    float tvv[TK]; int ti[TK];
    #pragma unroll
    for (int o = 0; o < TK; ++o) {
        float bv = v[0]; int bc = c[0];
        #pragma unroll
        for (int i = 1; i < 4; ++i) {
            bool take = (v[i] > bv) || (v[i] == bv && c[i] < bc);
            bv = take ? v[i] : bv;
            bc = take ? c[i] : bc;
        }
        #pragma unroll
        for (int off = 32; off; off >>= 1) {
            float ov = __shfl_xor(bv, off);
            int   oc = __shfl_xor(bc, off);
            bool take = (ov > bv) || (ov == bv && oc < bc);
            bv = take ? ov : bv;
            bc = take ? oc : bc;
        }
        tvv[o] = bv; ti[o] = bc;
        #pragma unroll
        for (int i = 0; i < 4; ++i)
            if (c[i] == bc) v[i] = NEG_BIG;
    }

    float p[TK]; float Z = 0.f;
    #pragma unroll
    for (int j = 0; j < TK; ++j) { p[j] = __expf(tvv[j] - tvv[0]); Z += p[j]; }
    const float invZ = __fdividef(1.f, Z);
    #pragma unroll
    for (int j = 0; j < TK; ++j) p[j] *= invZ;

    float4 eh = *(const float4*)(ehr + lane * 4);

    float4 nb[TK]; float kw[TK];
    #pragma unroll
    for (int k = 0; k < TK; ++k) {
        float4 n = *(const float4*)(e_t + (size_t)ti[k] * 256 + lane * 4);
        nb[k] = n;
        const float pk = p[k], qk = 1.f - p[k];
        float4 gt;
        gt.x = ftanh(eh.x + (pk * n.x + qk * eh.x));
        gt.y = ftanh(eh.y + (pk * n.y + qk * eh.y));
        gt.z = ftanh(eh.z + (pk * n.z + qk * eh.z));
        gt.w = ftanh(eh.w + (pk * n.w + qk * eh.w));
        float d = n.x*gt.x + n.y*gt.y + n.z*gt.z + n.w*gt.w;
        #pragma unroll
        for (int off = 32; off; off >>= 1) d += __shfl_xor(d, off);
        kw[k] = d;
    }

    float km = kw[0];
    #pragma unroll
    for (int k = 1; k < TK; ++k) km = fmaxf(km, kw[k]);
    float kz = 0.f; float kp[TK];
    #pragma unroll
    for (int k = 0; k < TK; ++k) { kp[k] = __expf(kw[k] - km); kz += kp[k]; }
    const float invKZ = __fdividef(1.f, kz);

    float4 acc = make_float4(0.f, 0.f, 0.f, 0.f);
    #pragma unroll
    for (int k = 0; k < TK; ++k) {
        acc.x += kp[k] * nb[k].x;
        acc.y += kp[k] * nb[k].y;
        acc.z += kp[k] * nb[k].z;
        acc.w += kp[k] * nb[k].w;
    }
    acc.x *= invKZ; acc.y *= invKZ; acc.z *= invKZ; acc.w *= invKZ;
    *(float4*)(e_Nh + (size_t)row * 256 + lane * 4) = acc;
}

// ---------------------------------------------------------------------------
extern "C" void kernel_launch(void* const* d_in, const int* in_sizes, int n_in,
                              void* d_out, int out_size, void* d_ws, size_t ws_size,
                              hipStream_t stream)
{
    (void)in_sizes; (void)n_in; (void)out_size; (void)ws_size;
    const float* x     = (const float*)d_in[0];
    const float* wsi_w = (const float*)d_in[1];
    const float* wsi_b = (const float*)d_in[2];
    const float* wh_w  = (const float*)d_in[3];
    const float* wh_b  = (const float*)d_in[4];
    const float* wt_w  = (const float*)d_in[5];
    const float* wt_b  = (const float*)d_in[6];
    const float* w1_w  = (const float*)d_in[7];
    const float* w1_b  = (const float*)d_in[8];
    const float* w2_w  = (const float*)d_in[9];
    const float* w2_b  = (const float*)d_in[10];
    float* out = (float*)d_out;
    float* ws  = (float*)d_ws;

    const int M = NROW;
    const size_t ND = (size_t)M * 256;            // 3,145,728

    float* h    = ws;                             // reused as e_Nh
    float* e_h  = ws + ND;
    float* e_t  = ws + 2*ND;
    _Float16* ehh = (_Float16*)(ws + 3*ND);       // ND halfs
    _Float16* eth = (_Float16*)(ws + 3*ND + ND/2);
    size_t o = 4*ND;
    unsigned* g32 = (unsigned*)(ws + o);          o += (size_t)NGRP_TOT*NROW;      // u32/group/row
    unsigned char* gcol = (unsigned char*)(ws + o); o += (size_t)NGRP_TOT*NROW/4;  // u8/group/row
    unsigned int* cnt = (unsigned int*)(ws + o);  o += NROW;
    int* cand = (int*)(ws + o);                   o += (size_t)NROW*CAP;
    _Float16* hp = (_Float16*)(ws + o);
    _Float16* wsiH = hp;                 // 1024*256 halfs
    _Float16* wsiL = hp + 262144;
    _Float16* w4base = hp + 524288;      // wh{H,L}, wt{H,L}, w1{H,L}, w2{H,L}
    _Float16* whH  = w4base;
    _Float16* whL  = w4base + 65536;
    _Float16* wtH  = w4base + 2*65536;
    _Float16* wtL  = w4base + 3*65536;
    _Float16* w1H  = w4base + 4*65536;
    _Float16* w1L  = w4base + 5*65536;
    _Float16* w2H  = w4base + 6*65536;
    _Float16* w2L  = w4base + 7*65536;
    float* e_Nh = h;

    // pack all five weights into fragment layout (single launch)
    wpack_all<<<256, 256, 0, stream>>>(wsi_w, wsiH, wsiL,
                                       wh_w, wt_w, w1_w, w2_w, w4base);

    // K1: h = relu(x @ wsi + b)  (128-col blocks: x streamed 2x not 4x)
    gemm_k1<<<dim3(2, M/64), 256, 0, stream>>>(
        x, wsiH, wsiL, wsi_b, h, 1024);
    // K2 fused: e_h, e_t + packed ehh (x SCALE), eth in epilogue
    gemm_dual<0><<<dim3(4, M/64), 256, 0, stream>>>(
        h, nullptr, whH, whL, wtH, wtL, wh_b, wt_b, e_h, e_t, ehh, eth);
    // S1: single score pass -> per-group (max1, col1, max2), [row][group]
    s1_gmax<<<NCH*96, 256, 0, stream>>>(ehh, eth, g32, gcol);
    // B2: tau + candidate emission (wave per row)
    b2_emit<<<M/4, 256, 0, stream>>>(g32, gcol, cnt, cand);
    // S3: scattered exact rescoring (fast-math) + attention tail -> e_Nh
    s3_tail<<<M/4, 256, 0, stream>>>(e_h, e_t, cnt, cand, e_Nh);
    // K5 fused: out = relu((e_h+e_Nh)@w1+b1) + relu((e_h*e_Nh)@w2+b2)
    gemm_dual<1><<<dim3(4, M/64), 256, 0, stream>>>(
        e_h, e_Nh, w1H, w1L, w2H, w2L, w1_b, w2_b, out, nullptr, nullptr, nullptr);
}

// Round 24
// 298.292 us; speedup vs baseline: 1.0089x; 1.0089x over previous
//
#include <hip/hip_runtime.h>
#include <hip/hip_bf16.h>
#include <cmath>

#define TK 12
#define NROW 12288
#define NEG_BIG (-3.0e38f)
#define MFMA16(a,b,c) __builtin_amdgcn_mfma_f32_16x16x32_f16(a,b,c,0,0,0)

#define NCH 8
#define CTILES 96
#define NPH 48
#define NGRP_TOT 384
#define CAP 256

typedef _Float16 f16x8 __attribute__((ext_vector_type(8)));
typedef _Float16 f16x4 __attribute__((ext_vector_type(4)));
typedef float    f32x4 __attribute__((ext_vector_type(4)));

typedef __attribute__((address_space(1))) const void gvoid_t;
typedef __attribute__((address_space(3))) void lvoid_t;
__device__ __forceinline__ void gload_lds16(const void* g, void* l) {
    __builtin_amdgcn_global_load_lds((gvoid_t*)g, (lvoid_t*)l, 16, 0, 0);
}

__device__ __forceinline__ float ftanh(float x) {
    float e = __expf(2.f * x);               // native v_exp; inf/0 saturate to +/-1
    return 1.f - __fdividef(2.f, e + 1.f);
}

// ---------------------------------------------------------------------------
// wpack_all: single launch packing all five weights into fragment layout.
// ---------------------------------------------------------------------------
__global__ __launch_bounds__(256) void wpack_all(
    const float* __restrict__ Wsi, _Float16* __restrict__ wsiH,
    _Float16* __restrict__ wsiL,
    const float* __restrict__ W0, const float* __restrict__ W1,
    const float* __restrict__ W2, const float* __restrict__ W3,
    _Float16* __restrict__ base)
{
    const int bx = blockIdx.x;
    if (bx < 128) {
        const int tid = bx * 256 + threadIdx.x;       // 0..32767
        const int l = tid & 63;
        const int s = (tid >> 6) & 31;                // nkt = 32
        const int cg = tid >> 11;
        const int krow = s * 32 + 8 * (l >> 4);
        const int col = cg * 16 + (l & 15);
        f16x8 H, L;
        #pragma unroll
        for (int j = 0; j < 8; ++j) {
            float w = Wsi[(size_t)(krow + j) * 256 + col];
            _Float16 h = (_Float16)w;
            H[j] = h;
            L[j] = (_Float16)(w - (float)h);
        }
        *(f16x8*)(wsiH + (size_t)tid * 8) = H;
        *(f16x8*)(wsiL + (size_t)tid * 8) = L;
    } else {
        const int m = (bx - 128) >> 5;
        const float* W = (m == 0) ? W0 : (m == 1) ? W1 : (m == 2) ? W2 : W3;
        _Float16* hi = base + (size_t)m * 131072;
        _Float16* lo = hi + 65536;
        const int tid = ((bx - 128) & 31) * 256 + threadIdx.x;   // 0..8191
        const int l = tid & 63;
        const int s = (tid >> 6) & 7;                 // nkt = 8
        const int cg = tid >> 9;
        const int krow = s * 32 + 8 * (l >> 4);
        const int col = cg * 16 + (l & 15);
        f16x8 H, L;
        #pragma unroll
        for (int j = 0; j < 8; ++j) {
            float w = W[(size_t)(krow + j) * 256 + col];
            _Float16 h = (_Float16)w;
            H[j] = h;
            L[j] = (_Float16)(w - (float)h);
        }
        *(f16x8*)(hi + (size_t)tid * 8) = H;
        *(f16x8*)(lo + (size_t)tid * 8) = L;
    }
}

// ---------------------------------------------------------------------------
// gemm_k1: C = relu( A @ W + bias ), K=1024. Grid (2,192): x streamed 2x.
// ---------------------------------------------------------------------------
__global__ __launch_bounds__(256) void gemm_k1(
    const float* __restrict__ A1,
    const _Float16* __restrict__ Wh, const _Float16* __restrict__ Wl,
    const float* __restrict__ bias, float* __restrict__ C, int K)
{
    __shared__ _Float16 aH[2048], aL[2048];
    __shared__ _Float16 wH[4096], wL[4096];
    const int tid = threadIdx.x, lane = tid & 63, wave = tid >> 6;
    const int rb = blockIdx.y * 64;
    const int cbg = blockIdx.x * 8;
    const int nkt = K >> 5;                       // 32

    const int arow = rb + wave * 16 + (lane & 15);
    const int acol0 = 8 * (lane >> 4);
    const float* a1p = A1 + (size_t)arow * K + acol0;

    const int slot0 = tid, slot1 = tid + 256;
    const size_t wbase0 = ((size_t)(cbg + (slot0 >> 6)) * nkt) * 512 + (slot0 & 63) * 8;
    const size_t wbase1 = ((size_t)(cbg + (slot1 >> 6)) * nkt) * 512 + (slot1 & 63) * 8;

    f32x4 acc[4][2];
    #pragma unroll
    for (int rg = 0; rg < 4; ++rg) {
        acc[rg][0] = (f32x4){0.f,0.f,0.f,0.f};
        acc[rg][1] = (f32x4){0.f,0.f,0.f,0.f};
    }

    float4 pa0 = *(const float4*)(a1p);
    float4 pa1 = *(const float4*)(a1p + 4);
    f16x8 pw0h = *(const f16x8*)(Wh + wbase0);
    f16x8 pw0l = *(const f16x8*)(Wl + wbase0);
    f16x8 pw1h = *(const f16x8*)(Wh + wbase1);
    f16x8 pw1l = *(const f16x8*)(Wl + wbase1);

    for (int kt = 0; kt < nkt; ++kt) {
        __syncthreads();
        {
            float v[8] = {pa0.x, pa0.y, pa0.z, pa0.w, pa1.x, pa1.y, pa1.z, pa1.w};
            f16x8 H, L;
            #pragma unroll
            for (int j = 0; j < 8; ++j) {
                _Float16 h = (_Float16)v[j];
                H[j] = h;
                L[j] = (_Float16)(v[j] - (float)h);
            }
            *(f16x8*)&aH[tid*8] = H;
            *(f16x8*)&aL[tid*8] = L;
            *(f16x8*)&wH[slot0*8] = pw0h;
            *(f16x8*)&wL[slot0*8] = pw0l;
            *(f16x8*)&wH[slot1*8] = pw1h;
            *(f16x8*)&wL[slot1*8] = pw1l;
        }
        __syncthreads();
        if (kt + 1 < nkt) {
            pa0 = *(const float4*)(a1p + (kt+1)*32);
            pa1 = *(const float4*)(a1p + (kt+1)*32 + 4);
            pw0h = *(const f16x8*)(Wh + wbase0 + (size_t)(kt+1)*512);
            pw0l = *(const f16x8*)(Wl + wbase0 + (size_t)(kt+1)*512);
            pw1h = *(const f16x8*)(Wh + wbase1 + (size_t)(kt+1)*512);
            pw1l = *(const f16x8*)(Wl + wbase1 + (size_t)(kt+1)*512);
        }
        f16x8 whA = *(const f16x8*)&wH[((wave*2+0)*64 + lane)*8];
        f16x8 wlA = *(const f16x8*)&wL[((wave*2+0)*64 + lane)*8];
        f16x8 whB = *(const f16x8*)&wH[((wave*2+1)*64 + lane)*8];
        f16x8 wlB = *(const f16x8*)&wL[((wave*2+1)*64 + lane)*8];
        #pragma unroll
        for (int rg = 0; rg < 4; ++rg) {
            f16x8 ah = *(const f16x8*)&aH[(rg*64 + lane)*8];
            f16x8 al = *(const f16x8*)&aL[(rg*64 + lane)*8];
            acc[rg][0] = MFMA16(whA, ah, acc[rg][0]);
            acc[rg][0] = MFMA16(wlA, ah, acc[rg][0]);
            acc[rg][0] = MFMA16(whA, al, acc[rg][0]);
            acc[rg][1] = MFMA16(whB, ah, acc[rg][1]);
            acc[rg][1] = MFMA16(wlB, ah, acc[rg][1]);
            acc[rg][1] = MFMA16(whB, al, acc[rg][1]);
        }
    }
    #pragma unroll
    for (int c = 0; c < 2; ++c) {
        const int col = (cbg + wave*2 + c)*16 + 4*(lane >> 4);
        float4 b4 = *(const float4*)(bias + col);
        #pragma unroll
        for (int rg = 0; rg < 4; ++rg) {
            const int row = rb + rg*16 + (lane & 15);
            float4 o;
            o.x = fmaxf(acc[rg][c][0] + b4.x, 0.f);
            o.y = fmaxf(acc[rg][c][1] + b4.y, 0.f);
            o.z = fmaxf(acc[rg][c][2] + b4.z, 0.f);
            o.w = fmaxf(acc[rg][c][3] + b4.w, 0.f);
            *(float4*)(C + (size_t)row*256 + col) = o;
        }
    }
}

// ---------------------------------------------------------------------------
// gemm_dual: K=N=256 fused pair, register-prefetched staging.
// ---------------------------------------------------------------------------
template<int DMODE>
__global__ __launch_bounds__(256) void gemm_dual(
    const float* __restrict__ A1, const float* __restrict__ A2,
    const _Float16* __restrict__ W1h, const _Float16* __restrict__ W1l,
    const _Float16* __restrict__ W2h, const _Float16* __restrict__ W2l,
    const float* __restrict__ bias1, const float* __restrict__ bias2,
    float* __restrict__ C1, float* __restrict__ C2,
    _Float16* __restrict__ P1, _Float16* __restrict__ P2)
{
    __shared__ _Float16 aH[2][2048], aL[2][2048];
    __shared__ _Float16 wH[2][2048], wL[2][2048];
    const int tid = threadIdx.x, lane = tid & 63, wave = tid >> 6;
    const int rb = blockIdx.y * 64;
    const int cbg = blockIdx.x * 4;

    const int arow = rb + wave * 16 + (lane & 15);
    const int acol0 = 8 * (lane >> 4);
    const float* a1p = A1 + (size_t)arow * 256 + acol0;
    const float* a2p = (DMODE == 1) ? (A2 + (size_t)arow * 256 + acol0) : nullptr;
    const size_t wbase = ((size_t)(cbg + wave) * 8) * 512 + lane * 8;

    f32x4 acc1[4], acc2[4];
    #pragma unroll
    for (int rg = 0; rg < 4; ++rg) {
        acc1[rg] = (f32x4){0.f,0.f,0.f,0.f};
        acc2[rg] = (f32x4){0.f,0.f,0.f,0.f};
    }

    float4 pa0 = *(const float4*)(a1p);
    float4 pa1 = *(const float4*)(a1p + 4);
    float4 pb0, pb1;
    if (DMODE == 1) { pb0 = *(const float4*)(a2p); pb1 = *(const float4*)(a2p + 4); }
    f16x8 pw1h = *(const f16x8*)(W1h + wbase);
    f16x8 pw1l = *(const f16x8*)(W1l + wbase);
    f16x8 pw2h = *(const f16x8*)(W2h + wbase);
    f16x8 pw2l = *(const f16x8*)(W2l + wbase);

    for (int kt = 0; kt < 8; ++kt) {
        __syncthreads();
        {
            float v[8] = {pa0.x, pa0.y, pa0.z, pa0.w, pa1.x, pa1.y, pa1.z, pa1.w};
            if (DMODE == 0) {
                f16x8 H, L;
                #pragma unroll
                for (int j = 0; j < 8; ++j) {
                    _Float16 h = (_Float16)v[j];
                    H[j] = h;
                    L[j] = (_Float16)(v[j] - (float)h);
                }
                *(f16x8*)&aH[0][tid*8] = H;
                *(f16x8*)&aL[0][tid*8] = L;
            } else {
                float b[8] = {pb0.x, pb0.y, pb0.z, pb0.w, pb1.x, pb1.y, pb1.z, pb1.w};
                f16x8 Hs, Ls, Hm, Lm;
                #pragma unroll
                for (int j = 0; j < 8; ++j) {
                    float s = v[j] + b[j];
                    float m = v[j] * b[j];
                    _Float16 hs = (_Float16)s;
                    _Float16 hm = (_Float16)m;
                    Hs[j] = hs; Ls[j] = (_Float16)(s - (float)hs);
                    Hm[j] = hm; Lm[j] = (_Float16)(m - (float)hm);
                }
                *(f16x8*)&aH[0][tid*8] = Hs;
                *(f16x8*)&aL[0][tid*8] = Ls;
                *(f16x8*)&aH[1][tid*8] = Hm;
                *(f16x8*)&aL[1][tid*8] = Lm;
            }
            *(f16x8*)&wH[0][tid*8] = pw1h;
            *(f16x8*)&wL[0][tid*8] = pw1l;
            *(f16x8*)&wH[1][tid*8] = pw2h;
            *(f16x8*)&wL[1][tid*8] = pw2l;
        }
        __syncthreads();
        if (kt + 1 < 8) {
            pa0 = *(const float4*)(a1p + (kt+1)*32);
            pa1 = *(const float4*)(a1p + (kt+1)*32 + 4);
            if (DMODE == 1) {
                pb0 = *(const float4*)(a2p + (kt+1)*32);
                pb1 = *(const float4*)(a2p + (kt+1)*32 + 4);
            }
            pw1h = *(const f16x8*)(W1h + wbase + (size_t)(kt+1)*512);
            pw1l = *(const f16x8*)(W1l + wbase + (size_t)(kt+1)*512);
            pw2h = *(const f16x8*)(W2h + wbase + (size_t)(kt+1)*512);
            pw2l = *(const f16x8*)(W2l + wbase + (size_t)(kt+1)*512);
        }
        f16x8 w1h = *(const f16x8*)&wH[0][(wave*64 + lane)*8];
        f16x8 w1l = *(const f16x8*)&wL[0][(wave*64 + lane)*8];
        f16x8 w2h = *(const f16x8*)&wH[1][(wave*64 + lane)*8];
        f16x8 w2l = *(const f16x8*)&wL[1][(wave*64 + lane)*8];
        #pragma unroll
        for (int rg = 0; rg < 4; ++rg) {
            f16x8 ah0 = *(const f16x8*)&aH[0][(rg*64 + lane)*8];
            f16x8 al0 = *(const f16x8*)&aL[0][(rg*64 + lane)*8];
            acc1[rg] = MFMA16(w1h, ah0, acc1[rg]);
            acc1[rg] = MFMA16(w1l, ah0, acc1[rg]);
            acc1[rg] = MFMA16(w1h, al0, acc1[rg]);
            f16x8 ah1 = (DMODE == 1) ? *(const f16x8*)&aH[1][(rg*64 + lane)*8] : ah0;
            f16x8 al1 = (DMODE == 1) ? *(const f16x8*)&aL[1][(rg*64 + lane)*8] : al0;
            acc2[rg] = MFMA16(w2h, ah1, acc2[rg]);
            acc2[rg] = MFMA16(w2l, ah1, acc2[rg]);
            acc2[rg] = MFMA16(w2h, al1, acc2[rg]);
        }
    }
    const int col = (cbg + wave)*16 + 4*(lane >> 4);
    float4 b14 = *(const float4*)(bias1 + col);
    float4 b24 = *(const float4*)(bias2 + col);
    #pragma unroll
    for (int rg = 0; rg < 4; ++rg) {
        const int row = rb + rg*16 + (lane & 15);
        if (DMODE == 0) {
            float4 o1, o2;
            o1.x = acc1[rg][0] + b14.x; o1.y = acc1[rg][1] + b14.y;
            o1.z = acc1[rg][2] + b14.z; o1.w = acc1[rg][3] + b14.w;
            o2.x = acc2[rg][0] + b24.x; o2.y = acc2[rg][1] + b24.y;
            o2.z = acc2[rg][2] + b24.z; o2.w = acc2[rg][3] + b24.w;
            *(float4*)(C1 + (size_t)row*256 + col) = o1;
            *(float4*)(C2 + (size_t)row*256 + col) = o2;
            const size_t poff = ((size_t)(row >> 4)*8 + (col >> 5))*512
                              + (((col & 31) >> 3)*16 + (row & 15))*8 + (col & 7);
            f16x4 p1, p2;
            p1[0] = (_Float16)(o1.x * 0.0625f); p1[1] = (_Float16)(o1.y * 0.0625f);
            p1[2] = (_Float16)(o1.z * 0.0625f); p1[3] = (_Float16)(o1.w * 0.0625f);
            p2[0] = (_Float16)o2.x; p2[1] = (_Float16)o2.y;
            p2[2] = (_Float16)o2.z; p2[3] = (_Float16)o2.w;
            *(f16x4*)(P1 + poff) = p1;
            *(f16x4*)(P2 + poff) = p2;
        } else {
            float4 o;
            o.x = fmaxf(acc1[rg][0] + b14.x, 0.f) + fmaxf(acc2[rg][0] + b24.x, 0.f);
            o.y = fmaxf(acc1[rg][1] + b14.y, 0.f) + fmaxf(acc2[rg][1] + b24.y, 0.f);
            o.z = fmaxf(acc1[rg][2] + b14.z, 0.f) + fmaxf(acc2[rg][2] + b24.z, 0.f);
            o.w = fmaxf(acc1[rg][3] + b14.w, 0.f) + fmaxf(acc2[rg][3] + b24.w, 0.f);
            *(float4*)(C1 + (size_t)row*256 + col) = o;
        }
    }
}

// ---------------------------------------------------------------------------
// S1 (rs=2, TOP-2, 4-TILE phases): per 32-col group and row, record
// (max1, col1, max2) into g32[row*384+g] and gcol (u8 col1).
// 24 phases (was 48): each phase covers 4 tiles = 2 groups -> half the
// barriers/fences/vmcnt drains. 2 x 32KB buffers, depth-1 prefetch
// (8 loads/phase issued at phase start, drained by phase-end vmcnt(0)).
// Flush every 4 phases = 8 groups, 32B+8B contiguous runs. Output layout
// byte-identical to 2-tile version -> b2/s3 unchanged.
// Grid = 8 chunks x 96 rowblocks = 768 blocks, 128 rows/block.
// ---------------------------------------------------------------------------
__global__ __launch_bounds__(256, 2) void s1_gmax(
    const _Float16* __restrict__ ehh, const _Float16* __restrict__ eth,
    unsigned* __restrict__ g32, unsigned char* __restrict__ gcol)
{
    __shared__ _Float16 abuf[2][16384];         // 2 x 32KB phase buffers (4 tiles)
    const int tid = threadIdx.x, lane = tid & 63, wave = tid >> 6;
    const int chunk = blockIdx.x & (NCH-1);     // == XCD id (L2 affinity)
    const int rblk = blockIdx.x >> 3;           // 0..95
    const int rg0 = rblk * 8 + wave * 2;

    f16x8 bh[2][8];
    #pragma unroll
    for (int rs = 0; rs < 2; ++rs) {
        const _Float16* p = ehh + (size_t)(rg0 + rs)*4096 + lane*8;
        #pragma unroll
        for (int s = 0; s < 8; ++s) bh[rs][s] = *(const f16x8*)(p + s*512);
    }
    #pragma unroll
    for (int rs = 0; rs < 2; ++rs)
        #pragma unroll
        for (int s = 0; s < 8; ++s)
            asm volatile("" : "+v"(bh[rs][s]));

    const int rsw = (lane >> 4) & 1;
    const int myrow = (rg0 + rsw)*16 + (lane & 15);
    const size_t rowbase = (size_t)myrow*NGRP_TOT + chunk*NPH;

    const _Float16* gsrc = eth + (size_t)chunk * CTILES * 4096;
    // prologue: stage phase 0 (4 tiles, 8 units/wave: u = wave*8+i, tile u>>3, k u&7)
    #pragma unroll
    for (int i = 0; i < 8; ++i) {
        const int u = wave*8 + i;
        gload_lds16(gsrc + (size_t)(u>>3)*4096 + (u&7)*512 + lane*8,
                    &abuf[0][u*512]);
    }
    asm volatile("s_waitcnt vmcnt(0) lgkmcnt(0)" ::: "memory");
    __builtin_amdgcn_s_barrier();
    asm volatile("" ::: "memory");

    int cur = 0;
    for (int pp = 0; pp < 6; ++pp) {
        unsigned resv[8];
        unsigned long long colv = 0;
        #pragma unroll
        for (int q = 0; q < 4; ++q) {
            const int p = pp*4 + q;                 // phase 0..23
            if (p + 1 < 24) {
                #pragma unroll
                for (int i = 0; i < 8; ++i) {
                    const int u = wave*8 + i;
                    gload_lds16(gsrc + (size_t)((p+1)*4 + (u>>3))*4096 + (u&7)*512 + lane*8,
                                &abuf[cur ^ 1][u*512]);
                }
            }
            // two 32-col groups per phase: gg=0 -> tiles 0,1; gg=1 -> tiles 2,3
            #pragma unroll
            for (int gg = 0; gg < 2; ++gg) {
                float m1a = NEG_BIG, m2a = NEG_BIG; int mca = 0;
                float m1b = NEG_BIG, m2b = NEG_BIG; int mcb = 0;
                #pragma unroll
                for (int tt = 0; tt < 2; ++tt) {
                    const int tile = gg*2 + tt;
                    f32x4 aE[2], aO[2];
                    #pragma unroll
                    for (int rs = 0; rs < 2; ++rs) {
                        aE[rs] = (f32x4){0.f,0.f,0.f,0.f};
                        aO[rs] = (f32x4){0.f,0.f,0.f,0.f};
                    }
                    #pragma unroll
                    for (int s = 0; s < 8; ++s) {
                        f16x8 ah = *(const f16x8*)&abuf[cur][tile*4096 + s*512 + lane*8];
                        if (s & 1) {
                            aO[0] = MFMA16(ah, bh[0][s], aO[0]);
                            aO[1] = MFMA16(ah, bh[1][s], aO[1]);
                        } else {
                            aE[0] = MFMA16(ah, bh[0][s], aE[0]);
                            aE[1] = MFMA16(ah, bh[1][s], aE[1]);
                        }
                    }
                    f32x4 a0 = aE[0] + aO[0];
                    f32x4 a1 = aE[1] + aO[1];
                    const int cb = tt*16 + 4*(lane >> 4);
                    #pragma unroll
                    for (int e = 0; e < 4; ++e) {
                        bool g0 = a0[e] > m1a;
                        m2a = fmaxf(m2a, g0 ? m1a : a0[e]);
                        mca = g0 ? (cb + e) : mca;
                        m1a = fmaxf(m1a, a0[e]);
                        bool g1 = a1[e] > m1b;
                        m2b = fmaxf(m2b, g1 ? m1b : a1[e]);
                        mcb = g1 ? (cb + e) : mcb;
                        m1b = fmaxf(m1b, a1[e]);
                    }
                }
                #pragma unroll
                for (int k = 16; k <= 32; k <<= 1) {
                    float o1 = __shfl_xor(m1a, k); int oc = __shfl_xor(mca, k);
                    float o2 = __shfl_xor(m2a, k);
                    bool gt = o1 > m1a;
                    m2a = fmaxf(fmaxf(m2a, o2), gt ? m1a : o1);
                    mca = gt ? oc : mca;
                    m1a = fmaxf(m1a, o1);
                    float p1 = __shfl_xor(m1b, k); int pc = __shfl_xor(mcb, k);
                    float p2 = __shfl_xor(m2b, k);
                    bool ht = p1 > m1b;
                    m2b = fmaxf(fmaxf(m2b, p2), ht ? m1b : p1);
                    mcb = ht ? pc : mcb;
                    m1b = fmaxf(m1b, p1);
                }
                {
                    float M1 = rsw ? m1b : m1a;
                    float M2 = rsw ? m2b : m2a;
                    int   MC = rsw ? mcb : mca;
                    unsigned short h1 = __builtin_bit_cast(unsigned short, (_Float16)M1);
                    unsigned short h2 = __builtin_bit_cast(unsigned short, (_Float16)M2);
                    const int slot = q*2 + gg;
                    resv[slot] = ((unsigned)h1 << 16) | h2;
                    colv |= (unsigned long long)(unsigned char)MC << (8*slot);
                }
            }
            if (q == 3 && lane < 32) {
                const size_t base = rowbase + pp*8;
                uint4 v0; v0.x = resv[0]; v0.y = resv[1]; v0.z = resv[2]; v0.w = resv[3];
                uint4 v1; v1.x = resv[4]; v1.y = resv[5]; v1.z = resv[6]; v1.w = resv[7];
                *(uint4*)(g32 + base)     = v0;
                *(uint4*)(g32 + base + 4) = v1;
                *(unsigned long long*)(gcol + base) = colv;
            }
            asm volatile("s_waitcnt vmcnt(0)" ::: "memory");
            __builtin_amdgcn_s_barrier();
            asm volatile("" ::: "memory");
            cur ^= 1;
        }
    }
    asm volatile("s_waitcnt vmcnt(0)" ::: "memory");
}

// ---------------------------------------------------------------------------
// B2 (wave-per-row): tau = (12th-largest max1) - margin; emit candidates.
// Grid = 3072 blocks x 4 waves.
// ---------------------------------------------------------------------------
__global__ __launch_bounds__(256) void b2_emit(
    const unsigned* __restrict__ g32, const unsigned char* __restrict__ gcol,
    unsigned* __restrict__ cnt, int* __restrict__ cand)
{
    const int lane = threadIdx.x & 63;
    const int wave = threadIdx.x >> 6;
    const int row  = blockIdx.x * 4 + wave;

    const unsigned* gr = g32 + (size_t)row*NGRP_TOT + lane*6;
    uint2 u0 = *(const uint2*)gr;
    uint2 u1 = *(const uint2*)(gr + 2);
    uint2 u2 = *(const uint2*)(gr + 4);
    unsigned uu[6] = {u0.x, u0.y, u1.x, u1.y, u2.x, u2.y};
    float m1[6], m2[6];
    #pragma unroll
    for (int i = 0; i < 6; ++i) {
        m1[i] = (float)__builtin_bit_cast(_Float16, (unsigned short)(uu[i] >> 16));
        m2[i] = (float)__builtin_bit_cast(_Float16, (unsigned short)(uu[i] & 0xffffu));
    }

    float sl[6];
    #pragma unroll
    for (int j = 0; j < 6; ++j) sl[j] = NEG_BIG;
    #pragma unroll
    for (int i = 0; i < 6; ++i) {
        float v = m1[i];
        #pragma unroll
        for (int j = 5; j >= 1; --j)
            sl[j] = __builtin_amdgcn_fmed3f(v, sl[j], sl[j-1]);
        sl[0] = fmaxf(v, sl[0]);
    }

    int hi = 0;
    float t12 = NEG_BIG;
    #pragma unroll 1
    for (int o = 0; o < TK; ++o) {
        float head = (hi < 6) ? sl[hi] : NEG_BIG;
        float bv = head; int bl = lane;
        #pragma unroll
        for (int off = 1; off <= 32; off <<= 1) {
            float ov = __shfl_xor(bv, off);
            int   ol = __shfl_xor(bl, off);
            bool take = (ov > bv) || (ov == bv && ol < bl);
            bv = take ? ov : bv;
            bl = take ? ol : bl;
        }
        if (lane == bl) hi++;
        t12 = bv;
    }
    const float tau = t12 - 0.02f;

    int n = 0;
    int* crow = cand + (size_t)row * CAP;
    #pragma unroll 1
    for (int i = 0; i < 6; ++i) {
        const bool hit1 = m1[i] >= tau;
        const bool expn = hit1 && (m2[i] >= tau);
        const bool single = hit1 && !expn;
        unsigned long long ms = __ballot(single);
        if (single) {
            const int pos = n + __popcll(ms & ((1ull << lane) - 1ull));
            if (pos < CAP) {
                const int g = lane*6 + i;
                crow[pos] = g*32 + (int)gcol[(size_t)row*NGRP_TOT + g];
            }
        }
        n += __popcll(ms);
        unsigned long long me = __ballot(expn);
        while (me) {
            const int src = __builtin_ctzll(me);
            me &= me - 1ull;
            const int cb = (src*6 + i) * 32;
            if (lane < 32) {
                const int pos = n + lane;
                if (pos < CAP) crow[pos] = cb + lane;
            }
            n += 32;
        }
    }
    if (lane == 0) cnt[row] = (unsigned)((n < CAP) ? n : CAP);
}

// ---------------------------------------------------------------------------
// S3 (scattered + FAST tanh/exp): exact f32 rescoring of up to 256
// candidates (4 per lane), exact top-12 (val desc, col asc), softmax /
// gather / tanh-gate / ka-softmax / e_Nh. One wave per row, 4 rows/block.
// ---------------------------------------------------------------------------
__global__ __launch_bounds__(256) void s3_tail(
    const float* __restrict__ e_h, const float* __restrict__ e_t,
    const unsigned int* __restrict__ cnt, const int* __restrict__ cand,
    float* __restrict__ e_Nh)
{
    const int lane = threadIdx.x & 63;
    const int wave = threadIdx.x >> 6;
    const int row  = blockIdx.x * 4 + wave;

    const unsigned cn = min(cnt[row], (unsigned)CAP);
    const float* ehr = e_h + (size_t)row * 256;

    float v[4]; int c[4];
    #pragma unroll
    for (int i = 0; i < 4; ++i) {
        const int idx = lane + 64*i;
        const bool act = idx < (int)cn;
        c[i] = act ? cand[(size_t)row*CAP + idx] : (0x7ffffff0 + i);
        v[i] = NEG_BIG;
        if ((int)cn > 64*i) {                    // wave-uniform chunk guard
            const float* etr = e_t + (size_t)(act ? c[i] : 0) * 256;
            float s = 0.f;
            for (int k = 0; k < 64; ++k) {
                float4 a = *(const float4*)(ehr + k*4);
                float4 b = *(const float4*)(etr + k*4);
                s += a.x*b.x + a.y*b.y + a.z*b.z + a.w*b.w;
            }
            if (act) v[i] = s * 0.0625f;
        }
    }

    float tvv[TK]; int ti[TK];
    #pragma unroll
    for (int o = 0; o < TK; ++o) {
        float bv = v[0]; int bc = c[0];
        #pragma unroll
        for (int i = 1; i < 4; ++i) {
            bool take = (v[i] > bv) || (v[i] == bv && c[i] < bc);
            bv = take ? v[i] : bv;
            bc = take ? c[i] : bc;
        }
        #pragma unroll
        for (int off = 32; off; off >>= 1) {
            float ov = __shfl_xor(bv, off);
            int   oc = __shfl_xor(bc, off);
            bool take = (ov > bv) || (ov == bv && oc < bc);
            bv = take ? ov : bv;
            bc = take ? oc : bc;
        }
        tvv[o] = bv; ti[o] = bc;
        #pragma unroll
        for (int i = 0; i < 4; ++i)
            if (c[i] == bc) v[i] = NEG_BIG;
    }

    float p[TK]; float Z = 0.f;
    #pragma unroll
    for (int j = 0; j < TK; ++j) { p[j] = __expf(tvv[j] - tvv[0]); Z += p[j]; }
    const float invZ = __fdividef(1.f, Z);
    #pragma unroll
    for (int j = 0; j < TK; ++j) p[j] *= invZ;

    float4 eh = *(const float4*)(ehr + lane * 4);

    float4 nb[TK]; float kw[TK];
    #pragma unroll
    for (int k = 0; k < TK; ++k) {
        float4 n = *(const float4*)(e_t + (size_t)ti[k] * 256 + lane * 4);
        nb[k] = n;
        const float pk = p[k], qk = 1.f - p[k];
        float4 gt;
        gt.x = ftanh(eh.x + (pk * n.x + qk * eh.x));
        gt.y = ftanh(eh.y + (pk * n.y + qk * eh.y));
        gt.z = ftanh(eh.z + (pk * n.z + qk * eh.z));
        gt.w = ftanh(eh.w + (pk * n.w + qk * eh.w));
        float d = n.x*gt.x + n.y*gt.y + n.z*gt.z + n.w*gt.w;
        #pragma unroll
        for (int off = 32; off; off >>= 1) d += __shfl_xor(d, off);
        kw[k] = d;
    }

    float km = kw[0];
    #pragma unroll
    for (int k = 1; k < TK; ++k) km = fmaxf(km, kw[k]);
    float kz = 0.f; float kp[TK];
    #pragma unroll
    for (int k = 0; k < TK; ++k) { kp[k] = __expf(kw[k] - km); kz += kp[k]; }
    const float invKZ = __fdividef(1.f, kz);

    float4 acc = make_float4(0.f, 0.f, 0.f, 0.f);
    #pragma unroll
    for (int k = 0; k < TK; ++k) {
        acc.x += kp[k] * nb[k].x;
        acc.y += kp[k] * nb[k].y;
        acc.z += kp[k] * nb[k].z;
        acc.w += kp[k] * nb[k].w;
    }
    acc.x *= invKZ; acc.y *= invKZ; acc.z *= invKZ; acc.w *= invKZ;
    *(float4*)(e_Nh + (size_t)row * 256 + lane * 4) = acc;
}

// ---------------------------------------------------------------------------
extern "C" void kernel_launch(void* const* d_in, const int* in_sizes, int n_in,
                              void* d_out, int out_size, void* d_ws, size_t ws_size,
                              hipStream_t stream)
{
    (void)in_sizes; (void)n_in; (void)out_size; (void)ws_size;
    const float* x     = (const float*)d_in[0];
    const float* wsi_w = (const float*)d_in[1];
    const float* wsi_b = (const float*)d_in[2];
    const float* wh_w  = (const float*)d_in[3];
    const float* wh_b  = (const float*)d_in[4];
    const float* wt_w  = (const float*)d_in[5];
    const float* wt_b  = (const float*)d_in[6];
    const float* w1_w  = (const float*)d_in[7];
    const float* w1_b  = (const float*)d_in[8];
    const float* w2_w  = (const float*)d_in[9];
    const float* w2_b  = (const float*)d_in[10];
    float* out = (float*)d_out;
    float* ws  = (float*)d_ws;

    const int M = NROW;
    const size_t ND = (size_t)M * 256;            // 3,145,728

    float* h    = ws;                             // reused as e_Nh
    float* e_h  = ws + ND;
    float* e_t  = ws + 2*ND;
    _Float16* ehh = (_Float16*)(ws + 3*ND);       // ND halfs
    _Float16* eth = (_Float16*)(ws + 3*ND + ND/2);
    size_t o = 4*ND;
    unsigned* g32 = (unsigned*)(ws + o);          o += (size_t)NGRP_TOT*NROW;      // u32/group/row
    unsigned char* gcol = (unsigned char*)(ws + o); o += (size_t)NGRP_TOT*NROW/4;  // u8/group/row
    unsigned int* cnt = (unsigned int*)(ws + o);  o += NROW;
    int* cand = (int*)(ws + o);                   o += (size_t)NROW*CAP;
    _Float16* hp = (_Float16*)(ws + o);
    _Float16* wsiH = hp;                 // 1024*256 halfs
    _Float16* wsiL = hp + 262144;
    _Float16* w4base = hp + 524288;      // wh{H,L}, wt{H,L}, w1{H,L}, w2{H,L}
    _Float16* whH  = w4base;
    _Float16* whL  = w4base + 65536;
    _Float16* wtH  = w4base + 2*65536;
    _Float16* wtL  = w4base + 3*65536;
    _Float16* w1H  = w4base + 4*65536;
    _Float16* w1L  = w4base + 5*65536;
    _Float16* w2H  = w4base + 6*65536;
    _Float16* w2L  = w4base + 7*65536;
    float* e_Nh = h;

    // pack all five weights into fragment layout (single launch)
    wpack_all<<<256, 256, 0, stream>>>(wsi_w, wsiH, wsiL,
                                       wh_w, wt_w, w1_w, w2_w, w4base);

    // K1: h = relu(x @ wsi + b)  (128-col blocks: x streamed 2x not 4x)
    gemm_k1<<<dim3(2, M/64), 256, 0, stream>>>(
        x, wsiH, wsiL, wsi_b, h, 1024);
    // K2 fused: e_h, e_t + packed ehh (x SCALE), eth in epilogue
    gemm_dual<0><<<dim3(4, M/64), 256, 0, stream>>>(
        h, nullptr, whH, whL, wtH, wtL, wh_b, wt_b, e_h, e_t, ehh, eth);
    // S1: single score pass -> per-group (max1, col1, max2), [row][group]
    s1_gmax<<<NCH*96, 256, 0, stream>>>(ehh, eth, g32, gcol);
    // B2: tau + candidate emission (wave per row)
    b2_emit<<<M/4, 256, 0, stream>>>(g32, gcol, cnt, cand);
    // S3: scattered exact rescoring (fast-math) + attention tail -> e_Nh
    s3_tail<<<M/4, 256, 0, stream>>>(e_h, e_t, cnt, cand, e_Nh);
    // K5 fused: out = relu((e_h+e_Nh)@w1+b1) + relu((e_h*e_Nh)@w2+b2)
    gemm_dual<1><<<dim3(4, M/64), 256, 0, stream>>>(
        e_h, e_Nh, w1H, w1L, w2H, w2L, w1_b, w2_b, out, nullptr, nullptr, nullptr);
}